// Round 5
// baseline (74.326 us; speedup 1.0000x reference)
//
#include <hip/hip_runtime.h>
#include <stdint.h>

#define Bn 8
#define Nn 2000
#define Cc 81
#define META_STRIDE (12 + Cc)
#define MAXI 100
#define MINCONF 0.7f
#define NMSTHR 0.3f
#define NPAD 2048
#define NW 32   // 64-bit words per mask row (2048 bits)

// map float to monotonically ordered uint (descending float == descending uint)
__device__ __forceinline__ uint32_t ford(float f) {
    uint32_t u = __float_as_uint(f);
    return (u & 0x80000000u) ? ~u : (u | 0x80000000u);
}

// ---------------- Kernel 1: per-ROI argmax, delta apply, clip, sort key ----
__global__ void k_prep(const float* __restrict__ rois,
                       const float* __restrict__ probs,
                       const float* __restrict__ bbox,
                       const float* __restrict__ meta,
                       float* __restrict__ refined,
                       float* __restrict__ score,
                       int* __restrict__ cls,
                       unsigned long long* __restrict__ keys) {
    int t = blockIdx.x * blockDim.x + threadIdx.x;
    if (t >= Bn * Nn) return;
    int b = t / Nn;
    int i = t - b * Nn;

    const float* p = probs + (size_t)t * Cc;
    int   cbest = 0;
    float sbest = p[0];
    for (int c = 1; c < Cc; ++c) {
        float v = p[c];
        if (v > sbest) { sbest = v; cbest = c; }   // first max wins (strict >)
    }

    const float* d = bbox + ((size_t)t * Cc + (size_t)cbest) * 4;
    float dy = d[0] * 0.1f, dx = d[1] * 0.1f, dh = d[2] * 0.2f, dw = d[3] * 0.2f;

    const float* r = rois + (size_t)t * 4;
    float y1 = r[0], x1 = r[1], y2 = r[2], x2 = r[3];
    float h = y2 - y1, w = x2 - x1;
    float cy = y1 + 0.5f * h + dy * h;
    float cx = x1 + 0.5f * w + dx * w;
    h = h * expf(dh);
    w = w * expf(dw);
    float ny1 = cy - 0.5f * h, nx1 = cx - 0.5f * w;
    float ny2 = cy + 0.5f * h, nx2 = cx + 0.5f * w;

    // window = (meta[b,7:11] - [0,0,1,1]) / ([h,w,h,w]-1), image shape from meta row 0
    float sy = meta[4] - 1.0f, sx = meta[5] - 1.0f;
    const float* mb = meta + (size_t)b * META_STRIDE;
    float wy1 = mb[7] / sy;
    float wx1 = mb[8] / sx;
    float wy2 = (mb[9]  - 1.0f) / sy;
    float wx2 = (mb[10] - 1.0f) / sx;

    ny1 = fminf(fmaxf(ny1, wy1), wy2);
    nx1 = fminf(fmaxf(nx1, wx1), wx2);
    ny2 = fminf(fmaxf(ny2, wy1), wy2);
    nx2 = fminf(fmaxf(nx2, wx1), wx2);

    refined[4 * t + 0] = ny1;
    refined[4 * t + 1] = nx1;
    refined[4 * t + 2] = ny2;
    refined[4 * t + 3] = nx2;
    score[t] = sbest;
    cls[t]   = cbest;

    bool valid = (cbest > 0) && (sbest >= MINCONF);
    float ks = valid ? sbest : -1.0f;
    keys[t] = ((unsigned long long)ford(ks) << 32) |
              (unsigned long long)(0xFFFFFFFFu - (uint32_t)i);
}

// ---------------- Kernel 2: per-batch bitonic sort (desc), V, sorted boxes --
__global__ void __launch_bounds__(1024, 1)
k_sort(const unsigned long long* __restrict__ keys,
       const float* __restrict__ refined,
       const int* __restrict__ cls,
       uint32_t* __restrict__ sidx,
       float* __restrict__ sbox,
       int* __restrict__ Vout) {
    __shared__ unsigned long long sk[NPAD];
    __shared__ int sV;
    int b = blockIdx.x, tid = threadIdx.x;

    const unsigned long long* kb = keys + (size_t)b * Nn;
    for (int t = tid; t < NPAD; t += 1024)
        sk[t] = (t < Nn) ? kb[t] : 0ull;      // pads sort to the very end
    if (tid == 0) sV = 0;
    __syncthreads();

    for (int k = 2; k <= NPAD; k <<= 1) {
        for (int j = k >> 1; j > 0; j >>= 1) {
            for (int t = tid; t < NPAD; t += 1024) {
                int ixj = t ^ j;
                if (ixj > t) {
                    unsigned long long a = sk[t], c = sk[ixj];
                    bool desc = ((t & k) == 0);
                    if (desc ? (a < c) : (a > c)) { sk[t] = c; sk[ixj] = a; }
                }
            }
            __syncthreads();
        }
    }

    // valid entries (top bit set: score>=0.7>0) form a prefix; find its length
    for (int t = tid; t < Nn; t += 1024) {
        bool v0 = (sk[t] >> 63) != 0ull;
        bool v1 = (t + 1 < Nn) ? ((sk[t + 1] >> 63) != 0ull) : false;
        if (v0 && !v1) sV = t + 1;            // single boundary -> single writer
    }
    __syncthreads();
    if (tid == 0) Vout[b] = sV;

    for (int t = tid; t < Nn; t += 1024) {
        uint32_t oi = 0xFFFFFFFFu - (uint32_t)(sk[t] & 0xFFFFFFFFull);
        sidx[b * Nn + t] = oi;
        int gi = b * Nn + (int)oi;
        float off = 4.0f * (float)cls[gi];    // CLASS_OFFSET * class_id
        sbox[(size_t)(b * Nn + t) * 4 + 0] = refined[gi * 4 + 0] + off;
        sbox[(size_t)(b * Nn + t) * 4 + 1] = refined[gi * 4 + 1] + off;
        sbox[(size_t)(b * Nn + t) * 4 + 2] = refined[gi * 4 + 2] + off;
        sbox[(size_t)(b * Nn + t) * 4 + 3] = refined[gi * 4 + 3] + off;
    }
}

// ---------------- Kernel 3: IoU suppression bitmask rows, one wave per row --
// Row i word w bit l = 1  <=>  j = w*64+l, j > i, j < V, IoU(i,j) > thr.
// Word i>>6 is the "diagonal" word: intra-block suppression bits.
__global__ void k_iou(const float* __restrict__ sbox,
                      const int* __restrict__ Vbuf,
                      unsigned long long* __restrict__ mask) {
    int gt   = blockIdx.x * blockDim.x + threadIdx.x;
    int wid  = gt >> 6;
    int lane = threadIdx.x & 63;
    if (wid >= Bn * Nn) return;
    int b = wid / Nn, i = wid - b * Nn;
    int V = Vbuf[b];
    if (i >= V) return;

    const float* bb = sbox + (size_t)(b * Nn + i) * 4;
    float y1 = bb[0], x1 = bb[1], y2 = bb[2], x2 = bb[3];
    float ar = (y2 - y1) * (x2 - x1);

    unsigned long long* row = mask + ((size_t)(b * Nn) + (size_t)i) * NW;
    int w0 = i >> 6, wlast = (V - 1) >> 6;
    for (int w = w0; w <= wlast; ++w) {
        int j = (w << 6) + lane;
        bool sup = false;
        if (j > i && j < V) {
            const float* cb = sbox + (size_t)(b * Nn + j) * 4;
            float oy1 = cb[0], ox1 = cb[1], oy2 = cb[2], ox2 = cb[3];
            float a2 = (oy2 - oy1) * (ox2 - ox1);
            float iy = fmaxf(0.0f, fminf(y2, oy2) - fmaxf(y1, oy1));
            float ix = fmaxf(0.0f, fminf(x2, ox2) - fmaxf(x1, ox1));
            float inter = iy * ix;
            float iou = inter / (ar + a2 - inter + 1e-12f);
            sup = iou > NMSTHR;
        }
        unsigned long long ball = __ballot(sup);
        if (lane == 0) row[w] = ball;
    }
}

// ---------------- Kernel 4: greedy scan, incremental rem[], parallel emit ---
// rem[w] accumulates OR of kept rows' word w (merged by 30 lanes in parallel
// at keep-time); intra-block suppression comes from prefetched diagonal words
// broadcast via __shfl. Single wave per batch; in-order DS ops make LDS
// write->read safe without barriers.
__global__ void __launch_bounds__(64, 1)
k_scan(const unsigned long long* __restrict__ mask,
       const int* __restrict__ Vbuf,
       const uint32_t* __restrict__ sidx,
       const float* __restrict__ refined,
       const float* __restrict__ score,
       const int* __restrict__ cls,
       float* __restrict__ out) {
    int b = blockIdx.x, lane = threadIdx.x;   // 64 threads = 1 wave
    __shared__ unsigned long long rem[NW];
    __shared__ int klist[128];                // capped at MAXI=100 by early break

    int V = Vbuf[b];
    int nblocks = (V + 63) >> 6;              // <= 32 = NW
    const unsigned long long* maskB = mask + (size_t)b * (size_t)Nn * NW;
    const uint32_t*           sidxB = sidx + (size_t)b * Nn;

    if (lane < NW) rem[lane] = 0ull;
    int nkept = 0;

    // prefetch block 0 diagonal words (row base+lane, word 0)
    unsigned long long diag_next = (lane < V) ? maskB[(size_t)lane * NW + 0] : 0ull;

    for (int t = 0; t < nblocks; ++t) {
        int base = t << 6;
        unsigned long long diag = diag_next;
        if (t + 1 < nblocks) {                // prefetch next diagonal early
            int j = base + 64 + lane;
            diag_next = (j < V) ? maskB[(size_t)j * NW + (t + 1)] : 0ull;
        }

        int nb = V - base; if (nb > 64) nb = 64;
        unsigned long long rmw = rem[t];      // broadcast LDS read; prior merges
                                              // ordered by in-wave DS ordering
        bool alive = (lane < nb) && !((rmw >> lane) & 1ull);
        unsigned long long candm = __ballot(alive);

        while (candm) {                       // one iteration per KEPT box
            int i = __builtin_ctzll(candm);
            if (lane == 0) klist[nkept] = base + i;
            ++nkept;
            if (nkept >= MAXI) break;         // output fully determined

            // merge kept row's FUTURE words into rem (parallel, one load/lane)
            int w = t + 1 + lane;
            if (w < nblocks)
                rem[w] |= maskB[(size_t)(base + i) * NW + w];

            // intra-block suppression by i via its diagonal word (lane i holds it)
            unsigned long long rowi = __shfl(diag, i, 64);
            alive = alive && !((rowi >> lane) & 1ull);
            candm = __ballot(alive) & ~((2ull << i) - 1ull);
        }
        if (nkept >= MAXI) break;
    }

    int ne = nkept < MAXI ? nkept : MAXI;
    for (int r = lane; r < ne; r += 64) {     // parallel emit
        int gi = b * Nn + (int)sidxB[klist[r]];
        float* orow = out + ((size_t)b * MAXI + r) * 6;
        orow[0] = refined[gi * 4 + 0];
        orow[1] = refined[gi * 4 + 1];
        orow[2] = refined[gi * 4 + 2];
        orow[3] = refined[gi * 4 + 3];
        orow[4] = (float)cls[gi];
        orow[5] = score[gi];
    }
    for (int tt = ne * 6 + lane; tt < MAXI * 6; tt += 64)
        out[(size_t)b * MAXI * 6 + tt] = 0.0f;
}

// ---------------- launch ----------------------------------------------------
extern "C" void kernel_launch(void* const* d_in, const int* in_sizes, int n_in,
                              void* d_out, int out_size, void* d_ws, size_t ws_size,
                              hipStream_t stream) {
    const float* rois  = (const float*)d_in[0];
    const float* probs = (const float*)d_in[1];
    const float* bbox  = (const float*)d_in[2];
    const float* meta  = (const float*)d_in[3];
    float* out = (float*)d_out;

    const int BN = Bn * Nn;
    char* ws = (char*)d_ws;
    size_t off = 0;
    auto alloc = [&](size_t bytes) {
        void* p = ws + off;
        off += (bytes + 255) & ~(size_t)255;
        return p;
    };
    float*              refined = (float*)              alloc((size_t)BN * 4 * sizeof(float));
    float*              score   = (float*)              alloc((size_t)BN * sizeof(float));
    int*                cls     = (int*)                alloc((size_t)BN * sizeof(int));
    unsigned long long* keys    = (unsigned long long*) alloc((size_t)BN * sizeof(unsigned long long));
    uint32_t*           sidx    = (uint32_t*)           alloc((size_t)BN * sizeof(uint32_t));
    float*              sbox    = (float*)              alloc((size_t)BN * 4 * sizeof(float));
    int*                Vbuf    = (int*)                alloc((size_t)Bn * sizeof(int));
    unsigned long long* mask    = (unsigned long long*) alloc((size_t)BN * NW * sizeof(unsigned long long));
    (void)ws_size; (void)in_sizes; (void)n_in; (void)out_size;

    k_prep<<<(BN + 255) / 256, 256, 0, stream>>>(rois, probs, bbox, meta,
                                                 refined, score, cls, keys);
    k_sort<<<Bn, 1024, 0, stream>>>(keys, refined, cls, sidx, sbox, Vbuf);
    k_iou<<<(BN * 64 + 255) / 256, 256, 0, stream>>>(sbox, Vbuf, mask);
    k_scan<<<Bn, 64, 0, stream>>>(mask, Vbuf, sidx, refined, score, cls, out);
}